// Round 1
// baseline (287.624 us; speedup 1.0000x reference)
//
#include <hip/hip_runtime.h>
#include <hip/hip_bf16.h>

// Problem constants (fixed by setup_inputs)
#define NB 4
#define SEQ 2048
#define HID 768
#define NSPAN 16384            // spans per batch
#define M_TOT (NB * NSPAN)     // 65536 rows
#define K2 1536                // 2*HID

typedef float f32x4 __attribute__((ext_vector_type(4)));
typedef short s16x8 __attribute__((ext_vector_type(8)));
using bf16 = __hip_bfloat16;

// ---------------------------------------------------------------------------
// Detect span_masks dtype: int32 (one 0/1 per word) vs byte-packed bools.
// Reading 16384 words = 64 KB is safe under either interpretation.
__global__ void mask_detect_kernel(const unsigned* __restrict__ masks, int* __restrict__ flag) {
    int t = blockIdx.x * 256 + threadIdx.x;
    if (t < 16384) {
        unsigned v = masks[t];
        if (v > 1u) atomicOr(flag, 1);   // multi-byte pattern => byte-packed bools
    }
}

// ---------------------------------------------------------------------------
// M3[b][c][p][h] = max over T[b, p .. p+c] (c = 0,1,2 => window 1,2,3), bf16.
// Rows with p+c >= SEQ are clamped garbage but provably never referenced.
__global__ void prep_m3_kernel(const float* __restrict__ T, bf16* __restrict__ M3) {
    int p = blockIdx.x;          // 0..SEQ-1
    int b = blockIdx.y;          // 0..NB-1
    int t = threadIdx.x;         // 256 threads
    int p1 = min(p + 1, SEQ - 1), p2 = min(p + 2, SEQ - 1);
    const float* r0 = T + ((size_t)b * SEQ + p)  * HID;
    const float* r1 = T + ((size_t)b * SEQ + p1) * HID;
    const float* r2 = T + ((size_t)b * SEQ + p2) * HID;
    bf16* o0 = M3 + ((size_t)(b * 3 + 0) * SEQ + p) * HID;
    bf16* o1 = M3 + ((size_t)(b * 3 + 1) * SEQ + p) * HID;
    bf16* o2 = M3 + ((size_t)(b * 3 + 2) * SEQ + p) * HID;
    for (int h = t; h < HID; h += 256) {
        float v0 = r0[h];
        float m2 = fmaxf(v0, r1[h]);
        float m3 = fmaxf(m2, r2[h]);
        o0[h] = __float2bfloat16(v0);
        o1[h] = __float2bfloat16(m2);
        o2[h] = __float2bfloat16(m3);
    }
}

// ---------------------------------------------------------------------------
// Wt[n][k] = bf16(W[k][n]); W is (K2, HID) f32 row-major. 64x64 LDS transpose.
__global__ void prep_wt_kernel(const float* __restrict__ W, bf16* __restrict__ Wt) {
    __shared__ float tile[64][65];
    int k0 = blockIdx.x * 64;    // 24 blocks
    int n0 = blockIdx.y * 64;    // 12 blocks
    int t = threadIdx.x;         // 256 threads
    int c = t & 63, r4 = t >> 6;
    for (int r = r4; r < 64; r += 4)
        tile[r][c] = W[(size_t)(k0 + r) * HID + n0 + c];
    __syncthreads();
    for (int r = r4; r < 64; r += 4)
        Wt[(size_t)(n0 + r) * K2 + k0 + c] = __float2bfloat16(tile[c][r]);
}

// ---------------------------------------------------------------------------
// GEMM: out[m][n] = mask[m] ? sum_k A[m][k]*W[k][n] + b[n] : b[n]
// A[m] = [ M3row(b,cw,s) | M3row(b,cw,e-cw) ]  (gathered, never materialized)
// 128x128 tile, 4 waves (2x2 of 64x64), BK=64, mfma_f32_16x16x32_bf16.
__global__ __launch_bounds__(256, 2)
void span_gemm_kernel(const bf16* __restrict__ M3, const bf16* __restrict__ Wt,
                      const int* __restrict__ span_ids, const int* __restrict__ masks,
                      const float* __restrict__ bias, const int* __restrict__ pooling,
                      const int* __restrict__ mask_mode, float* __restrict__ out) {
    __shared__ short lA[128][72];   // +8 pad: 144 B row stride -> 2-way bank alias (free)
    __shared__ short lB[128][72];
    __shared__ int rS[128], rE[128], rM[128];

    const int tid = threadIdx.x;
    const int n0 = blockIdx.x * 128;   // 6 col tiles
    const int m0 = blockIdx.y * 128;   // 512 row tiles

    const int window = (pooling[0] != 0) ? 1 : 3;
    const int u8mode = mask_mode[0];

    if (tid < 128) {
        int m = m0 + tid;
        int s = span_ids[2 * m], e = span_ids[2 * m + 1];
        int b = m >> 14;                       // m / NSPAN
        int cw = min(window, e - s);           // e-s >= 1 always
        int baseRow = (b * 3 + (cw - 1)) * SEQ;
        rS[tid] = baseRow + s;
        rE[tid] = baseRow + (e - cw);
        rM[tid] = u8mode ? (((const unsigned char*)masks)[m] != 0) : (masks[m] != 0);
    }
    __syncthreads();

    f32x4 acc[4][4];
#pragma unroll
    for (int i = 0; i < 4; i++)
#pragma unroll
        for (int j = 0; j < 4; j++) acc[i][j] = (f32x4){0.f, 0.f, 0.f, 0.f};

    const int w = tid >> 6, l = tid & 63;
    const int wr = w >> 1, wc = w & 1;       // wave 2x2
    const int lr = l & 15, lg = l >> 4;
    const int srow = tid >> 3;               // staging: 32 rows/pass
    const int scol = (tid & 7) * 8;          // 8 x 16B per row

    const short* M3s = (const short*)M3;
    const short* Wts = (const short*)Wt;

    for (int kt = 0; kt < K2; kt += 64) {
        const int half = kt >= HID;
        const int col = kt - (half ? HID : 0);
        const int* ridx = half ? rE : rS;
        __syncthreads();   // previous tile fully consumed
#pragma unroll
        for (int it = 0; it < 4; ++it) {
            int row = it * 32 + srow;
            const short* src = M3s + (size_t)ridx[row] * HID + col + scol;
            *(s16x8*)&lA[row][scol] = *(const s16x8*)src;
        }
#pragma unroll
        for (int it = 0; it < 4; ++it) {
            int row = it * 32 + srow;
            const short* src = Wts + (size_t)(n0 + row) * K2 + kt + scol;
            *(s16x8*)&lB[row][scol] = *(const s16x8*)src;
        }
        __syncthreads();
#pragma unroll
        for (int kk = 0; kk < 64; kk += 32) {
            const int klane = kk + lg * 8;
            s16x8 af[4], bf[4];
#pragma unroll
            for (int i = 0; i < 4; i++) af[i] = *(const s16x8*)&lA[wr * 64 + i * 16 + lr][klane];
#pragma unroll
            for (int j = 0; j < 4; j++) bf[j] = *(const s16x8*)&lB[wc * 64 + j * 16 + lr][klane];
#pragma unroll
            for (int i = 0; i < 4; i++)
#pragma unroll
                for (int j = 0; j < 4; j++)
                    acc[i][j] = __builtin_amdgcn_mfma_f32_16x16x32_bf16(af[i], bf[j], acc[i][j], 0, 0, 0);
        }
    }

    // Epilogue: C/D layout (verified m89): col = lane&15, row = (lane>>4)*4 + q
#pragma unroll
    for (int i = 0; i < 4; i++) {
#pragma unroll
        for (int j = 0; j < 4; j++) {
#pragma unroll
            for (int q = 0; q < 4; q++) {
                int mloc = wr * 64 + i * 16 + lg * 4 + q;
                int n = n0 + wc * 64 + j * 16 + lr;
                float v = rM[mloc] ? (acc[i][j][q] + bias[n]) : bias[n];
                out[(size_t)(m0 + mloc) * HID + n] = v;
            }
        }
    }
}

// ---------------------------------------------------------------------------
extern "C" void kernel_launch(void* const* d_in, const int* in_sizes, int n_in,
                              void* d_out, int out_size, void* d_ws, size_t ws_size,
                              hipStream_t stream) {
    const float* token_reps = (const float*)d_in[0];
    const int*   span_ids   = (const int*)d_in[1];
    const int*   span_masks = (const int*)d_in[2];
    const int*   pooling    = (const int*)d_in[3];
    const float* W          = (const float*)d_in[4];
    const float* bias       = (const float*)d_in[5];
    float* out = (float*)d_out;

    // ws layout: [0,4) mask-mode flag | [256, 256+37.75MB) M3 | then Wt (2.25MB)
    int*  flag = (int*)d_ws;
    bf16* M3   = (bf16*)((char*)d_ws + 256);
    const size_t M3_BYTES = (size_t)NB * 3 * SEQ * HID * 2;   // 37,748,736
    bf16* Wt   = (bf16*)((char*)d_ws + 256 + M3_BYTES);

    hipMemsetAsync(flag, 0, 4, stream);
    mask_detect_kernel<<<64, 256, 0, stream>>>((const unsigned*)span_masks, flag);
    prep_m3_kernel<<<dim3(SEQ, NB), 256, 0, stream>>>(token_reps, M3);
    prep_wt_kernel<<<dim3(K2 / 64, HID / 64), 256, 0, stream>>>(W, Wt);
    span_gemm_kernel<<<dim3(HID / 128, M_TOT / 128), 256, 0, stream>>>(
        M3, Wt, span_ids, span_masks, bias, pooling, flag, out);
}

// Round 2
// 192.420 us; speedup vs baseline: 1.4948x; 1.4948x over previous
//
#include <hip/hip_runtime.h>
#include <hip/hip_bf16.h>

// Problem constants (fixed by setup_inputs)
#define NB 4
#define SEQ 2048
#define HID 768
#define NSPAN 16384            // spans per batch
#define M_TOT (NB * NSPAN)     // 65536 rows
#define K2 1536                // 2*HID

typedef float f32x4 __attribute__((ext_vector_type(4)));
typedef short s16x8 __attribute__((ext_vector_type(8)));
using bf16 = __hip_bfloat16;

// global -> LDS direct (16B per lane). LDS dest is wave-uniform base + lane*16;
// global src is per-lane (gather-capable).
__device__ __forceinline__ void gll16(const void* g, void* l) {
    __builtin_amdgcn_global_load_lds(
        (const __attribute__((address_space(1))) unsigned*)g,
        (__attribute__((address_space(3))) unsigned*)l, 16, 0, 0);
}

// ---------------------------------------------------------------------------
// Detect span_masks dtype: int32 words (0/1) vs byte-packed bools.
__global__ void mask_detect_kernel(const unsigned* __restrict__ masks, int* __restrict__ flag) {
    int t = blockIdx.x * 256 + threadIdx.x;
    if (t < 16384) {
        unsigned v = masks[t];
        if (v > 1u) atomicOr(flag, 1);   // multi-byte pattern => byte-packed bools
    }
}

// ---------------------------------------------------------------------------
// M3[b][c][p][h] = max over T[b, p .. p+c] (c = 0,1,2 => window 1,2,3), bf16.
// Rows with p+c >= SEQ are clamped garbage but provably never referenced.
__global__ void prep_m3_kernel(const float* __restrict__ T, bf16* __restrict__ M3) {
    int p = blockIdx.x;
    int b = blockIdx.y;
    int t = threadIdx.x;
    int p1 = min(p + 1, SEQ - 1), p2 = min(p + 2, SEQ - 1);
    const float* r0 = T + ((size_t)b * SEQ + p)  * HID;
    const float* r1 = T + ((size_t)b * SEQ + p1) * HID;
    const float* r2 = T + ((size_t)b * SEQ + p2) * HID;
    bf16* o0 = M3 + ((size_t)(b * 3 + 0) * SEQ + p) * HID;
    bf16* o1 = M3 + ((size_t)(b * 3 + 1) * SEQ + p) * HID;
    bf16* o2 = M3 + ((size_t)(b * 3 + 2) * SEQ + p) * HID;
    for (int h = t; h < HID; h += 256) {
        float v0 = r0[h];
        float m2 = fmaxf(v0, r1[h]);
        float m3 = fmaxf(m2, r2[h]);
        o0[h] = __float2bfloat16(v0);
        o1[h] = __float2bfloat16(m2);
        o2[h] = __float2bfloat16(m3);
    }
}

// ---------------------------------------------------------------------------
// Wt[n][k] = bf16(W[k][n]); W is (K2, HID) f32 row-major. 64x64 LDS transpose.
__global__ void prep_wt_kernel(const float* __restrict__ W, bf16* __restrict__ Wt) {
    __shared__ float tile[64][65];
    int k0 = blockIdx.x * 64;
    int n0 = blockIdx.y * 64;
    int t = threadIdx.x;
    int c = t & 63, r4 = t >> 6;
    for (int r = r4; r < 64; r += 4)
        tile[r][c] = W[(size_t)(k0 + r) * HID + n0 + c];
    __syncthreads();
    for (int r = r4; r < 64; r += 4)
        Wt[(size_t)(n0 + r) * K2 + k0 + c] = __float2bfloat16(tile[c][r]);
}

// ---------------------------------------------------------------------------
// GEMM: out[m][n] = mask[m] ? sum_k A[m][k]*W[k][n] + b[n] : b[n]
// A[m] = [ M3row(b,cw,s) | M3row(b,cw,e-cw) ]  (gathered via per-lane
// global_load_lds source addresses, never materialized).
// 128x128 tile, 4 waves (2x2 of 64x64), BK=64, mfma_f32_16x16x32_bf16.
// LDS layout: linear [row][128B], 16B-chunk XOR-swizzled (chunk ^= row&7) on
// BOTH the global source and the ds_read side (rule 21: both-or-neither).
__global__ __launch_bounds__(256, 2)
void span_gemm_kernel(const bf16* __restrict__ M3, const bf16* __restrict__ Wt,
                      const int* __restrict__ span_ids, const int* __restrict__ masks,
                      const float* __restrict__ bias, const int* __restrict__ pooling,
                      const int* __restrict__ mask_mode, float* __restrict__ out) {
    __shared__ char lA[128 * 128];   // 16 KB
    __shared__ char lB[128 * 128];   // 16 KB
    __shared__ int rS[128], rE[128], rM[128];

    const int tid = threadIdx.x;
    const int n0 = blockIdx.x * 128;   // 6 col tiles
    const int m0 = blockIdx.y * 128;   // 512 row tiles

    const int window = (pooling[0] != 0) ? 1 : 3;
    const int u8mode = mask_mode[0];

    if (tid < 128) {
        int m = m0 + tid;
        int s = span_ids[2 * m], e = span_ids[2 * m + 1];
        int b = m >> 14;
        int cw = min(window, e - s);          // e-s >= 1 always
        int baseRow = (b * 3 + (cw - 1)) * SEQ;
        rS[tid] = baseRow + s;
        rE[tid] = baseRow + (e - cw);
        rM[tid] = u8mode ? (((const unsigned char*)masks)[m] != 0) : (masks[m] != 0);
    }
    __syncthreads();

    const int lane = tid & 63, w = tid >> 6;
    const int wr = w >> 1, wc = w & 1;        // wave 2x2 over the 128x128 tile
    const int lr = lane & 15, lg = lane >> 4;

    // Staging geometry: per K-step each operand is 128 rows x 128 B = 8KB
    // = 8 wave-issues of 1KB; 4 issues per thread per operand.
    // Lane covers (row = issue*8 + lane>>3, chunk = lane&7); source chunk is
    // XOR-swizzled by row&7.
    const int lrow8 = lane >> 3;
    const int chunkp = ((lane & 7) ^ lrow8) << 4;   // swizzled byte offset in row

    const char* aPtr[2][4];
    const char* bPtr[4];
    int ldsOff[4];
#pragma unroll
    for (int it = 0; it < 4; ++it) {
        int i = it * 4 + w;                    // 1KB-issue index 0..31
        int r = i * 8 + lrow8;                 // LDS row 0..127
        aPtr[0][it] = (const char*)M3 + (size_t)rS[r] * (HID * 2) + chunkp;
        aPtr[1][it] = (const char*)M3 + (size_t)rE[r] * (HID * 2) + chunkp;
        bPtr[it]    = (const char*)Wt + (size_t)(n0 + r) * (K2 * 2) + chunkp;
        ldsOff[it]  = i * 1024;                // wave-uniform
    }

    f32x4 acc[4][4];
#pragma unroll
    for (int i = 0; i < 4; i++)
#pragma unroll
        for (int j = 0; j < 4; j++) acc[i][j] = (f32x4){0.f, 0.f, 0.f, 0.f};

    for (int kt = 0; kt < K2; kt += 64) {
        const int half = (kt >= HID) ? 1 : 0;
        const int colB = (kt - (half ? HID : 0)) * 2;   // byte col within M3 row
        const int ktB  = kt * 2;                        // byte col within Wt row
        __syncthreads();   // previous tile fully consumed by all waves
#pragma unroll
        for (int it = 0; it < 4; ++it)
            gll16(aPtr[half][it] + colB, lA + ldsOff[it]);
#pragma unroll
        for (int it = 0; it < 4; ++it)
            gll16(bPtr[it] + ktB, lB + ldsOff[it]);
        __syncthreads();   // vmcnt(0) drained by compiler before barrier
#pragma unroll
        for (int kk = 0; kk < 2; ++kk) {
            const int cb = kk * 4 + lg;        // global 16B-chunk index (k/8)
            s16x8 af[4], bf[4];
#pragma unroll
            for (int i = 0; i < 4; ++i) {
                int row = wr * 64 + i * 16 + lr;
                af[i] = *(const s16x8*)(lA + row * 128 + ((cb ^ (row & 7)) << 4));
            }
#pragma unroll
            for (int j = 0; j < 4; ++j) {
                int row = wc * 64 + j * 16 + lr;
                bf[j] = *(const s16x8*)(lB + row * 128 + ((cb ^ (row & 7)) << 4));
            }
#pragma unroll
            for (int i = 0; i < 4; ++i)
#pragma unroll
                for (int j = 0; j < 4; ++j)
                    acc[i][j] = __builtin_amdgcn_mfma_f32_16x16x32_bf16(af[i], bf[j], acc[i][j], 0, 0, 0);
        }
    }

    // Epilogue: C/D layout (verified m89): col = lane&15, row = (lane>>4)*4 + q
#pragma unroll
    for (int i = 0; i < 4; i++) {
#pragma unroll
        for (int j = 0; j < 4; j++) {
#pragma unroll
            for (int q = 0; q < 4; q++) {
                int mloc = wr * 64 + i * 16 + lg * 4 + q;
                int n = n0 + wc * 64 + j * 16 + lr;
                float v = rM[mloc] ? (acc[i][j][q] + bias[n]) : bias[n];
                out[(size_t)(m0 + mloc) * HID + n] = v;
            }
        }
    }
}

// ---------------------------------------------------------------------------
extern "C" void kernel_launch(void* const* d_in, const int* in_sizes, int n_in,
                              void* d_out, int out_size, void* d_ws, size_t ws_size,
                              hipStream_t stream) {
    const float* token_reps = (const float*)d_in[0];
    const int*   span_ids   = (const int*)d_in[1];
    const int*   span_masks = (const int*)d_in[2];
    const int*   pooling    = (const int*)d_in[3];
    const float* W          = (const float*)d_in[4];
    const float* bias       = (const float*)d_in[5];
    float* out = (float*)d_out;

    // ws layout: [0,4) mask-mode flag | [256, +37.75MB) M3 | then Wt (2.25MB)
    int*  flag = (int*)d_ws;
    bf16* M3   = (bf16*)((char*)d_ws + 256);
    const size_t M3_BYTES = (size_t)NB * 3 * SEQ * HID * 2;
    bf16* Wt   = (bf16*)((char*)d_ws + 256 + M3_BYTES);

    hipMemsetAsync(flag, 0, 4, stream);
    mask_detect_kernel<<<64, 256, 0, stream>>>((const unsigned*)span_masks, flag);
    prep_m3_kernel<<<dim3(SEQ, NB), 256, 0, stream>>>(token_reps, M3);
    prep_wt_kernel<<<dim3(K2 / 64, HID / 64), 256, 0, stream>>>(W, Wt);
    span_gemm_kernel<<<dim3(HID / 128, M_TOT / 128), 256, 0, stream>>>(
        M3, Wt, span_ids, span_masks, bias, pooling, flag, out);
}